// Round 6
// baseline (73.037 us; speedup 1.0000x reference)
//
#include <hip/hip_runtime.h>

#define HH 1024
#define WW 1024
#define NPTS 512          // 16 segments * 32 samples = path points = edges
#define W_EPS 1e-6f       // drop edges whose row-weight is below this (err <= 512*eps)
#define ROWSTRIDE (NPTS + 1)   // float4 slots per row in ws: 1 header + up to 512 entries

__device__ __forceinline__ float sigmoidf(float z) {
    // 1/(1+exp(-z)); __expf underflows to 0 for very negative z -> sigmoid==1 exactly.
    float e = __expf(-z);
    return __builtin_amdgcn_rcpf(1.0f + e);
}

// Bezier path point i (wraps at 512): seg = i>>5, t = (i&31)/31
__device__ __forceinline__ float2 bez(const float* cpL, int i) {
    i &= (NPTS - 1);
    int seg = i >> 5;
    int j = i & 31;
    float t = (float)j * (1.0f / 31.0f);
    float mt = 1.0f - t;
    int b = 6 * seg;
    float a0 = mt * mt * mt;
    float a1 = 3.0f * mt * mt * t;
    float a2 = 3.0f * mt * t * t;
    float a3 = t * t * t;
    return make_float2(
        a0 * cpL[b+0] + a1 * cpL[b+2] + a2 * cpL[b+4] + a3 * cpL[b+6],
        a0 * cpL[b+1] + a1 * cpL[b+3] + a2 * cpL[b+5] + a3 * cpL[b+7]);
}

// ---------- Kernel A: per-row active-edge list -> ws ----------
__global__ __launch_bounds__(512) void prep_kernel(
    const float* __restrict__ cp,     // 49 x 2 control points
    float4* __restrict__ ws)          // [HH][ROWSTRIDE] float4
{
    __shared__ float  cpL[98];
    __shared__ float4 act[NPTS];      // (xc, w, tminf, tmaxf)
    __shared__ int    n_act;

    const int tid = threadIdx.x;
    const int y = blockIdx.x;
    const float yf = (float)y;

    if (tid == 0) n_act = 0;
    if (tid < 98) cpL[tid] = cp[tid];
    __syncthreads();

    // edge `tid`: weight for this row; classify per 64-px tile.
    //   tiles t <  tmin : fully saturated (add w)
    //   tiles t in [tmin, tmax] : transition window (eval sigma)
    {
        float2 p = bez(cpL, tid);
        float2 q = bez(cpL, tid + 1);
        float dy = q.y - p.y;
        float dx = q.x - p.x;
        float c = (dy > 0.0f) ? 1.0f : ((dy < 0.0f) ? -1.0f : 0.0f);
        if (fabsf(dy) < 1e-6f) c = 0.0f;
        float t = (yf - p.y) * __builtin_amdgcn_rcpf(dy + 1e-8f);
        float vt = sigmoidf(t * 20.0f) * sigmoidf((1.0f - t) * 20.0f);
        float w = vt * c;
        if (fabsf(w) > W_EPS) {
            float xc = fmaf(t, dx, p.x);
            int tmin = (int)ceilf((xc - 77.0f) * 0.015625f);
            tmin = max(0, min(16, tmin));
            int tmax = (int)floorf((xc + 14.0f) * 0.015625f);
            tmax = max(-1, min(15, tmax));
            int idx = atomicAdd(&n_act, 1);
            act[idx] = make_float4(xc, w, (float)tmin, (float)tmax);
        }
    }
    __syncthreads();

    float4* row = ws + y * ROWSTRIDE;
    const int n = n_act;
    if (tid == 0) *(int*)row = n;           // header
    if (tid < n) row[1 + tid] = act[tid];   // compact list
}

// ---------- Kernel B: render a quarter-row per block, no atomics ----------
__global__ __launch_bounds__(256) void render_kernel(
    const float4* __restrict__ ws,
    const float* __restrict__ color,  // 3 floats
    float* __restrict__ out)          // H x W x 4
{
    __shared__ float4 list[NPTS];

    const int tid = threadIdx.x;
    const int y = blockIdx.x >> 2;
    const int quarter = blockIdx.x & 3;
    const float4* rp = ws + y * ROWSTRIDE;

    const int n = *(const int*)rp;          // uniform -> scalar load
    for (int i = tid; i < n; i += 256) list[i] = rp[1 + i];
    __syncthreads();

    const int t = quarter * 4 + (tid >> 6); // 64-px tile id, wave-uniform
    const int lane = tid & 63;
    const float xf = (float)(t * 64 + lane);

    float acc = 0.0f;
    for (int i = 0; i < n; ++i) {
        float4 e = list[i];                 // wave-uniform broadcast
        int tmin = (int)e.z;
        int tmax = (int)e.w;
        if (t < tmin) {
            acc += e.y;                     // saturated: sigma == 1
        } else if (t <= tmax) {
            acc = fmaf(e.y, sigmoidf(e.x - xf), acc);
        }
        // else sigma == 0
    }

    float4* orow = ((float4*)out) + y * WW;
    orow[t * 64 + lane] = make_float4(color[0], color[1], color[2],
                                      sigmoidf(4.0f * acc));
}

extern "C" void kernel_launch(void* const* d_in, const int* in_sizes, int n_in,
                              void* d_out, int out_size, void* d_ws, size_t ws_size,
                              hipStream_t stream) {
    const float* cp = (const float*)d_in[0];
    const float* color = (const float*)d_in[1];
    float* out = (float*)d_out;
    float4* ws = (float4*)d_ws;             // 1024 * 513 * 16 B = 8.4 MB used

    prep_kernel<<<HH, 512, 0, stream>>>(cp, ws);
    render_kernel<<<HH * 4, 256, 0, stream>>>(ws, color, out);
}

// Round 7
// 66.629 us; speedup vs baseline: 1.0962x; 1.0962x over previous
//
#include <hip/hip_runtime.h>

#define HH 1024
#define WW 1024
#define NPTS 512          // 16 segments * 32 samples = path points = edges
#define TPB 256
#define W_EPS 1e-6f       // drop edges whose row-weight is below this (err <= 512*eps)
#define CAP 64            // per-quarter transition-list capacity (exact fallback if exceeded)

__device__ __forceinline__ float sigmoidf(float z) {
    // 1/(1+exp(-z)); __expf underflows to 0 for very negative z -> sigmoid==1 exactly.
    float e = __expf(-z);
    return __builtin_amdgcn_rcpf(1.0f + e);
}

// Bezier path point i: seg = i>>5, t = (i&31)/31
__device__ __forceinline__ float2 bez(const float* cpL, int i) {
    int seg = i >> 5;
    int j = i & 31;
    float t = (float)j * (1.0f / 31.0f);
    float mt = 1.0f - t;
    int b = 6 * seg;
    float a0 = mt * mt * mt;
    float a1 = 3.0f * mt * mt * t;
    float a2 = 3.0f * mt * t * t;
    float a3 = t * t * t;
    return make_float2(
        a0 * cpL[b+0] + a1 * cpL[b+2] + a2 * cpL[b+4] + a3 * cpL[b+6],
        a0 * cpL[b+1] + a1 * cpL[b+3] + a2 * cpL[b+5] + a3 * cpL[b+7]);
}

// One 256-px quarter-row per block. 4096 blocks x 256 threads, fully fused.
__global__ __launch_bounds__(TPB) void render_kernel(
    const float* __restrict__ cp,     // 49 x 2 control points
    const float* __restrict__ color,  // 3 floats
    float* __restrict__ out)          // H x W x 4
{
    __shared__ float  cpL[98];
    __shared__ float  colL[3];
    __shared__ float2 ptsL[NPTS];
    __shared__ float2 list[CAP];      // (xc, w) transition edges for this quarter
    __shared__ int    n_list;
    __shared__ float  satW;

    const int tid = threadIdx.x;
    const int y = blockIdx.x >> 2;
    const int q = blockIdx.x & 3;
    const float yf = (float)y;
    const float qlo = (float)(q * 256);
    const float qhi = qlo + 255.0f;

    if (tid < 98) cpL[tid] = cp[tid];
    if (tid < 3)  colL[tid] = color[tid];
    if (tid == 0) { n_list = 0; satW = 0.0f; }
    __syncthreads();

    // --- 1. path points (2 per thread) ---
    ptsL[tid]       = bez(cpL, tid);
    ptsL[tid + 256] = bez(cpL, tid + 256);
    __syncthreads();

    // --- 2. classify 2 edges/thread against THIS quarter ---
    //   saturated for whole quarter  <=> xc >= qhi + 14   (sigma >= 1-8e-7)
    //   negligible for whole quarter <=> xc <= qlo - 14
    //   else: transition -> list
    float mySat = 0.0f;
    #pragma unroll
    for (int k = 0; k < 2; ++k) {
        int e = tid + k * 256;
        float2 p = ptsL[e];
        float2 qq = ptsL[(e + 1) & (NPTS - 1)];
        float dy = qq.y - p.y;
        float dx = qq.x - p.x;
        float c = (dy > 0.0f) ? 1.0f : ((dy < 0.0f) ? -1.0f : 0.0f);
        if (fabsf(dy) < 1e-6f) c = 0.0f;
        float t = (yf - p.y) * __builtin_amdgcn_rcpf(dy + 1e-8f);
        float vt = sigmoidf(t * 20.0f) * sigmoidf((1.0f - t) * 20.0f);
        float w = vt * c;
        if (fabsf(w) > W_EPS) {
            float xc = fmaf(t, dx, p.x);
            if (xc >= qhi + 14.0f) {
                mySat += w;
            } else if (xc > qlo - 14.0f) {
                int pos = atomicAdd(&n_list, 1);
                if (pos < CAP) list[pos] = make_float2(xc, w);
            }
        }
    }
    // wave-reduce mySat, one LDS atomic per wave
    #pragma unroll
    for (int o = 32; o > 0; o >>= 1) mySat += __shfl_xor(mySat, o);
    if ((tid & 63) == 0) atomicAdd(&satW, mySat);
    __syncthreads();

    // --- 3. render: 1 px per thread ---
    const float xf = qlo + (float)tid;
    const int n = n_list;
    float acc;
    if (n <= CAP) {
        acc = satW;
        for (int i = 0; i < n; ++i) {
            float2 d = list[i];               // wave-uniform broadcast
            acc = fmaf(d.y, sigmoidf(d.x - xf), acc);
        }
    } else {
        // freak overflow: exact full scan of all edges
        acc = 0.0f;
        for (int e = 0; e < NPTS; ++e) {
            float2 p = ptsL[e];
            float2 qq = ptsL[(e + 1) & (NPTS - 1)];
            float dy = qq.y - p.y;
            float dx = qq.x - p.x;
            float c = (dy > 0.0f) ? 1.0f : ((dy < 0.0f) ? -1.0f : 0.0f);
            if (fabsf(dy) < 1e-6f) c = 0.0f;
            float t = (yf - p.y) * __builtin_amdgcn_rcpf(dy + 1e-8f);
            float vt = sigmoidf(t * 20.0f) * sigmoidf((1.0f - t) * 20.0f);
            float w = vt * c;
            if (fabsf(w) > W_EPS) {
                float xc = fmaf(t, dx, p.x);
                acc = fmaf(w, sigmoidf(xc - xf), acc);
            }
        }
    }

    float4* orow = ((float4*)out) + y * WW;
    orow[q * 256 + tid] = make_float4(colL[0], colL[1], colL[2],
                                      sigmoidf(4.0f * acc));
}

extern "C" void kernel_launch(void* const* d_in, const int* in_sizes, int n_in,
                              void* d_out, int out_size, void* d_ws, size_t ws_size,
                              hipStream_t stream) {
    const float* cp = (const float*)d_in[0];
    const float* color = (const float*)d_in[1];
    float* out = (float*)d_out;
    render_kernel<<<HH * 4, TPB, 0, stream>>>(cp, color, out);
}